// Round 2
// baseline (936.624 us; speedup 1.0000x reference)
//
#include <hip/hip_runtime.h>
#include <math.h>

// ---------------------------------------------------------------------------
// Problem: N=8192 tokens, D=4096, E=8 experts, R=16, top_k=2. ALL fp32 in/out.
// out = x @ W^T + sum_{e in top2} 2*w_e * (x @ A[e]^T) @ B[e]^T
// Strategy: convert x,W,A,B to bf16 in workspace; fold LoRA down-proj into the
// base GEMM as a K-extension: c[n, e*16+r] = bf16(2*w[n,e]*ax[n,e,r]), then
// out = [xb | c] @ [Wb | Bt]^T with K = 4096 + 128, fp32 accumulate, fp32 out.
// ---------------------------------------------------------------------------

#define NTOK 8192
#define DIM  4096
#define NEXP 8
#define RANK 16
#define KAUG (NEXP * RANK)   // 128

typedef __bf16 bf16x8 __attribute__((ext_vector_type(8)));
typedef float  f32x4  __attribute__((ext_vector_type(4)));

__device__ __forceinline__ unsigned short f2bf(float f) {
    union { float f; unsigned int u; } v;
    v.f = f;
    unsigned int u = v.u;
    return (unsigned short)((u + 0x7fffu + ((u >> 16) & 1u)) >> 16);
}

// ---------------------------------------------------------------------------
// Kernel 0: fp32 -> bf16 conversion (vectorized), used for x, W, A
// ---------------------------------------------------------------------------
__global__ __launch_bounds__(256) void k_cvt(
    const float4* __restrict__ in, ushort4* __restrict__ outv, int n4)
{
    int i = blockIdx.x * 256 + threadIdx.x;
    if (i < n4) {
        float4 v = in[i];
        outv[i] = make_ushort4(f2bf(v.x), f2bf(v.y), f2bf(v.z), f2bf(v.w));
    }
}

// ---------------------------------------------------------------------------
// Kernel 1: permute+convert B fp32 [E][D][R] -> Bt bf16 [D][E*R]
// ---------------------------------------------------------------------------
__global__ __launch_bounds__(256) void k_bt(
    const float* __restrict__ B, unsigned short* __restrict__ Bt)
{
    int idx = blockIdx.x * 256 + threadIdx.x;   // over DIM*KAUG = 524288
    int o = idx >> 7;
    int j = idx & 127;
    int e = j >> 4;
    int r = j & 15;
    Bt[idx] = f2bf(B[((size_t)e * DIM + o) * RANK + r]);
}

// ---------------------------------------------------------------------------
// Kernel 2: gate logits (fp32) + top-2 + softmax. One block per token.
// gate_out[n] = {(float)e0, (float)e1, w0, w1}
// ---------------------------------------------------------------------------
__global__ __launch_bounds__(256) void k_gate(
    const float* __restrict__ x,
    const float* __restrict__ gW,
    float4* __restrict__ gate_out)
{
    __shared__ float xs[DIM];
    __shared__ float logits[NEXP];
    const int n = blockIdx.x;

    const float4* xr = (const float4*)(x + (size_t)n * DIM);
    for (int c = threadIdx.x; c < DIM / 4; c += 256) {
        float4 v = xr[c];
        xs[4 * c + 0] = v.x;
        xs[4 * c + 1] = v.y;
        xs[4 * c + 2] = v.z;
        xs[4 * c + 3] = v.w;
    }
    __syncthreads();

    const int wave = threadIdx.x >> 6;
    const int lane = threadIdx.x & 63;
    for (int e = wave; e < NEXP; e += 4) {
        const float* g = gW + (size_t)e * DIM;
        float s = 0.f;
        for (int i = lane; i < DIM; i += 64) s += xs[i] * g[i];
        #pragma unroll
        for (int off = 32; off; off >>= 1) s += __shfl_down(s, off);
        if (lane == 0) logits[e] = s;
    }
    __syncthreads();

    if (threadIdx.x == 0) {
        int e0 = 0; float v0 = logits[0];
        #pragma unroll
        for (int e = 1; e < NEXP; ++e)
            if (logits[e] > v0) { v0 = logits[e]; e0 = e; }
        int e1 = -1; float v1 = -INFINITY;
        #pragma unroll
        for (int e = 0; e < NEXP; ++e)
            if (e != e0 && logits[e] > v1) { v1 = logits[e]; e1 = e; }
        float b = __expf(v1 - v0);          // softmax over [v0,v1], v0 >= v1
        float w0 = 1.f / (1.f + b);
        float w1 = 1.f - w0;
        gate_out[n] = make_float4((float)e0, (float)e1, w0, w1);
    }
}

// ---------------------------------------------------------------------------
// Shared GEMM machinery: 128x128 block tile, BK=64, 4 waves (2x2), each wave
// 4x4 fragments of mfma_f32_16x16x32_bf16. global_load_lds width=16 staging.
// LDS tile layout: [128 rows][64 k] bf16, row-major, contiguous (required by
// global_load_lds lane mapping: LDS addr = wave-uniform base + lane*16B).
// ---------------------------------------------------------------------------
__device__ __forceinline__ void stage_lds(
    const unsigned short* gbase, int strideElems,
    unsigned short* ldsBase, int wave, int lane)
{
    const int l8 = lane >> 3;          // 0..7  (row within 8-row chunk)
    const int c8 = (lane & 7) << 3;    // 0,8,...,56 (element col)
    #pragma unroll
    for (int q = 0; q < 4; ++q) {
        const int r = wave * 32 + q * 8;   // wave-uniform row base
        const unsigned short* gp = gbase + (size_t)(r + l8) * strideElems + c8;
        unsigned short* lp = ldsBase + r * 64;   // wave-uniform; HW adds lane*16B
        __builtin_amdgcn_global_load_lds(
            (const __attribute__((address_space(1))) void*)gp,
            (__attribute__((address_space(3))) void*)lp,
            16, 0, 0);
    }
}

__device__ __forceinline__ void mfma_step(
    const unsigned short* As, const unsigned short* Bs,
    int waveM, int waveN, int lane, f32x4 acc[4][4])
{
    const int quad = lane >> 4;
    const int l15  = lane & 15;
    #pragma unroll
    for (int s = 0; s < 2; ++s) {
        const int ko = s * 32 + quad * 8;
        bf16x8 af[4], bfv[4];
        #pragma unroll
        for (int i = 0; i < 4; ++i)
            af[i] = *(const bf16x8*)(As + (waveM * 64 + i * 16 + l15) * 64 + ko);
        #pragma unroll
        for (int j = 0; j < 4; ++j)
            bfv[j] = *(const bf16x8*)(Bs + (waveN * 64 + j * 16 + l15) * 64 + ko);
        #pragma unroll
        for (int i = 0; i < 4; ++i)
            #pragma unroll
            for (int j = 0; j < 4; ++j)
                acc[i][j] = __builtin_amdgcn_mfma_f32_16x16x32_bf16(
                    af[i], bfv[j], acc[i][j], 0, 0, 0);
    }
}

// ---------------------------------------------------------------------------
// Kernel 3: ax GEMM  xb[8192x4096] @ Ab[128x4096]^T, epilogue applies gate:
// cB[n,j] = bf16( (e(j)==e0 ? 2*w0 : e(j)==e1 ? 2*w1 : 0) * ax[n,j] )
// ---------------------------------------------------------------------------
__global__ __launch_bounds__(256) void k_ax(
    const unsigned short* __restrict__ xb,
    const unsigned short* __restrict__ Ab,     // [128][4096] bf16
    const float4* __restrict__ gate_out,
    unsigned short* __restrict__ cB)           // [8192][128] bf16
{
    __shared__ __align__(16) unsigned short As[128 * 64];
    __shared__ __align__(16) unsigned short Bs[128 * 64];
    const int tid  = threadIdx.x;
    const int wave = tid >> 6, lane = tid & 63;
    const int waveM = wave >> 1, waveN = wave & 1;
    const int rowBase = blockIdx.x * 128;

    f32x4 acc[4][4] = {};

    for (int it = 0; it < DIM / 64; ++it) {
        stage_lds(xb + (size_t)rowBase * DIM + it * 64, DIM, As, wave, lane);
        stage_lds(Ab + (size_t)it * 64,                 DIM, Bs, wave, lane);
        __syncthreads();
        mfma_step(As, Bs, waveM, waveN, lane, acc);
        __syncthreads();
    }

    const int quad = lane >> 4, l15 = lane & 15;
    #pragma unroll
    for (int i = 0; i < 4; ++i) {
        #pragma unroll
        for (int j = 0; j < 4; ++j) {
            const int gc = waveN * 64 + j * 16 + l15;   // 0..127
            const int e  = gc >> 4;
            #pragma unroll
            for (int t = 0; t < 4; ++t) {
                const int gr = rowBase + waveM * 64 + i * 16 + quad * 4 + t;
                float4 g = gate_out[gr];
                int e0 = (int)g.x;
                int e1 = (int)g.y;
                float scale = (e == e0) ? 2.f * g.z : (e == e1) ? 2.f * g.w : 0.f;
                cB[(size_t)gr * KAUG + gc] = f2bf(scale * acc[i][j][t]);
            }
        }
    }
}

// ---------------------------------------------------------------------------
// Kernel 4: main GEMM, K = 4096 (xb,Wb) + 128 (cB,Bt) -> fp32 out [8192][4096]
// ---------------------------------------------------------------------------
__global__ __launch_bounds__(256) void k_main(
    const unsigned short* __restrict__ xb,    // [8192][4096] bf16
    const unsigned short* __restrict__ Wb,    // [4096][4096] bf16
    const unsigned short* __restrict__ cB,    // [8192][128]  bf16
    const unsigned short* __restrict__ Bt,    // [4096][128]  bf16
    float* __restrict__ out)                  // [8192][4096] fp32
{
    __shared__ __align__(16) unsigned short As[128 * 64];
    __shared__ __align__(16) unsigned short Bs[128 * 64];
    const int tid  = threadIdx.x;
    const int wave = tid >> 6, lane = tid & 63;
    const int waveM = wave >> 1, waveN = wave & 1;
    const int rowBase = blockIdx.y * 128;
    const int colBase = blockIdx.x * 128;

    f32x4 acc[4][4] = {};

    for (int it = 0; it < DIM / 64; ++it) {
        stage_lds(xb + (size_t)rowBase * DIM + it * 64, DIM, As, wave, lane);
        stage_lds(Wb + (size_t)colBase * DIM + it * 64, DIM, Bs, wave, lane);
        __syncthreads();
        mfma_step(As, Bs, waveM, waveN, lane, acc);
        __syncthreads();
    }
    // LoRA K-extension: 2 iterations over K=128 from cB / Bt (stride 128)
    for (int it = 0; it < KAUG / 64; ++it) {
        stage_lds(cB + (size_t)rowBase * KAUG + it * 64, KAUG, As, wave, lane);
        stage_lds(Bt + (size_t)colBase * KAUG + it * 64, KAUG, Bs, wave, lane);
        __syncthreads();
        mfma_step(As, Bs, waveM, waveN, lane, acc);
        __syncthreads();
    }

    const int quad = lane >> 4, l15 = lane & 15;
    #pragma unroll
    for (int i = 0; i < 4; ++i) {
        #pragma unroll
        for (int j = 0; j < 4; ++j) {
            const int gc = colBase + waveN * 64 + j * 16 + l15;
            #pragma unroll
            for (int t = 0; t < 4; ++t) {
                const int gr = rowBase + waveM * 64 + i * 16 + quad * 4 + t;
                out[(size_t)gr * DIM + gc] = acc[i][j][t];
            }
        }
    }
}

// ---------------------------------------------------------------------------
extern "C" void kernel_launch(void* const* d_in, const int* in_sizes, int n_in,
                              void* d_out, int out_size, void* d_ws, size_t ws_size,
                              hipStream_t stream) {
    (void)in_sizes; (void)n_in; (void)out_size; (void)ws_size;

    const float* x  = (const float*)d_in[0];  // [8192][4096]
    const float* bW = (const float*)d_in[1];  // [4096][4096]
    const float* gW = (const float*)d_in[2];  // [8][4096]
    const float* A  = (const float*)d_in[3];  // [8][16][4096] = [128][4096]
    const float* B  = (const float*)d_in[4];  // [8][4096][16]
    // d_in[5] = top_k (always 2)
    float* out = (float*)d_out;

    // workspace layout (all regions fully rewritten every launch)
    char* ws = (char*)d_ws;
    float4*         gate_out = (float4*)ws;                         //   128 KiB
    unsigned short* xb = (unsigned short*)(ws + (1u << 17));        //    64 MiB
    unsigned short* Wb = xb + (size_t)NTOK * DIM;                   //    32 MiB
    unsigned short* Ab = Wb + (size_t)DIM * DIM;                    //     1 MiB
    unsigned short* Bt = Ab + (size_t)KAUG * DIM;                   //     1 MiB
    unsigned short* cB = Bt + (size_t)DIM * KAUG;                   //     2 MiB
                                                                    // ~100 MiB total

    k_cvt <<<(NTOK * DIM / 4 + 255) / 256, 256, 0, stream>>>(
        (const float4*)x, (ushort4*)xb, NTOK * DIM / 4);
    k_cvt <<<(DIM * DIM / 4 + 255) / 256, 256, 0, stream>>>(
        (const float4*)bW, (ushort4*)Wb, DIM * DIM / 4);
    k_cvt <<<(KAUG * DIM / 4 + 255) / 256, 256, 0, stream>>>(
        (const float4*)A, (ushort4*)Ab, KAUG * DIM / 4);
    k_bt  <<<(DIM * KAUG) / 256, 256, 0, stream>>>(B, Bt);
    k_gate<<<NTOK, 256, 0, stream>>>(x, gW, gate_out);
    k_ax  <<<NTOK / 128, 256, 0, stream>>>(xb, Ab, gate_out, cB);
    k_main<<<dim3(DIM / 128, NTOK / 128), 256, 0, stream>>>(xb, Wb, cB, Bt, out);
}

// Round 3
// 713.518 us; speedup vs baseline: 1.3127x; 1.3127x over previous
//
#include <hip/hip_runtime.h>
#include <math.h>

// ---------------------------------------------------------------------------
// Problem: N=8192 tokens, D=4096, E=8 experts, R=16, top_k=2. ALL fp32 in/out.
// out = x @ W^T + sum_{e in top2} 2*w_e * (x @ A[e]^T) @ B[e]^T
// Strategy: convert x,W,A,B to bf16 in ws; fold LoRA down-proj into the base
// GEMM as a K-extension (K = 4096 + 128), fp32 accumulate, fp32 out.
// LDS tiles use an XOR-8 swizzle (chunk ^= row&7) to kill ds_read_b128 bank
// conflicts; swizzle is applied in GLOBAL address space during staging since
// global_load_lds's LDS write pattern (base + lane*16B) is fixed.
// ---------------------------------------------------------------------------

#define NTOK 8192
#define DIM  4096
#define NEXP 8
#define RANK 16
#define KAUG (NEXP * RANK)   // 128
#define KSPLIT 4             // k_ax split-K factor

typedef __bf16 bf16x8 __attribute__((ext_vector_type(8)));
typedef float  f32x4  __attribute__((ext_vector_type(4)));

__device__ __forceinline__ unsigned short f2bf(float f) {
    union { float f; unsigned int u; } v;
    v.f = f;
    unsigned int u = v.u;
    return (unsigned short)((u + 0x7fffu + ((u >> 16) & 1u)) >> 16);
}

// ---------------------------------------------------------------------------
// Kernel 0: fp32 -> bf16 conversion (vectorized), used for W, A
// ---------------------------------------------------------------------------
__global__ __launch_bounds__(256) void k_cvt(
    const float4* __restrict__ in, ushort4* __restrict__ outv, int n4)
{
    int i = blockIdx.x * 256 + threadIdx.x;
    if (i < n4) {
        float4 v = in[i];
        outv[i] = make_ushort4(f2bf(v.x), f2bf(v.y), f2bf(v.z), f2bf(v.w));
    }
}

// ---------------------------------------------------------------------------
// Kernel 1: permute+convert B fp32 [E][D][R] -> Bt bf16 [D][E*R]
// ---------------------------------------------------------------------------
__global__ __launch_bounds__(256) void k_bt(
    const float* __restrict__ B, unsigned short* __restrict__ Bt)
{
    int idx = blockIdx.x * 256 + threadIdx.x;   // over DIM*KAUG = 524288
    int o = idx >> 7;
    int j = idx & 127;
    int e = j >> 4;
    int r = j & 15;
    Bt[idx] = f2bf(B[((size_t)e * DIM + o) * RANK + r]);
}

// ---------------------------------------------------------------------------
// Kernel 2: gate (fp32 logits + top-2 + softmax) FUSED with x fp32->bf16.
// One block per token. gate_out[n] = {(float)e0, (float)e1, w0, w1}
// ---------------------------------------------------------------------------
__global__ __launch_bounds__(256) void k_gate(
    const float* __restrict__ x,
    const float* __restrict__ gW,
    float4* __restrict__ gate_out,
    ushort4* __restrict__ xb4)                 // bf16 mirror of x
{
    __shared__ float xs[DIM];
    __shared__ float logits[NEXP];
    const int n = blockIdx.x;

    const float4* xr = (const float4*)(x + (size_t)n * DIM);
    ushort4* xw = xb4 + (size_t)n * (DIM / 4);
    for (int c = threadIdx.x; c < DIM / 4; c += 256) {
        float4 v = xr[c];
        xs[4 * c + 0] = v.x;
        xs[4 * c + 1] = v.y;
        xs[4 * c + 2] = v.z;
        xs[4 * c + 3] = v.w;
        xw[c] = make_ushort4(f2bf(v.x), f2bf(v.y), f2bf(v.z), f2bf(v.w));
    }
    __syncthreads();

    const int wave = threadIdx.x >> 6;
    const int lane = threadIdx.x & 63;
    for (int e = wave; e < NEXP; e += 4) {
        const float* g = gW + (size_t)e * DIM;
        float s = 0.f;
        for (int i = lane; i < DIM; i += 64) s += xs[i] * g[i];
        #pragma unroll
        for (int off = 32; off; off >>= 1) s += __shfl_down(s, off);
        if (lane == 0) logits[e] = s;
    }
    __syncthreads();

    if (threadIdx.x == 0) {
        int e0 = 0; float v0 = logits[0];
        #pragma unroll
        for (int e = 1; e < NEXP; ++e)
            if (logits[e] > v0) { v0 = logits[e]; e0 = e; }
        int e1 = -1; float v1 = -INFINITY;
        #pragma unroll
        for (int e = 0; e < NEXP; ++e)
            if (e != e0 && logits[e] > v1) { v1 = logits[e]; e1 = e; }
        float b = __expf(v1 - v0);          // softmax over [v0,v1], v0 >= v1
        float w0 = 1.f / (1.f + b);
        float w1 = 1.f - w0;
        gate_out[n] = make_float4((float)e0, (float)e1, w0, w1);
    }
}

// ---------------------------------------------------------------------------
// Shared GEMM machinery: 128x128 block tile, BK=64, 4 waves (2x2), each wave
// 4x4 fragments of mfma_f32_16x16x32_bf16. global_load_lds width=16 staging.
// LDS tile: [128 rows][8 chunks of 8 bf16]; PHYSICAL chunk = logical ^ (row&7).
// Staging achieves this by loading global chunk ((lane&7) ^ l8) for row l8.
// ---------------------------------------------------------------------------
__device__ __forceinline__ void stage_lds(
    const unsigned short* gbase, int strideElems,
    unsigned short* ldsBase, int wave, int lane)
{
    const int l8 = lane >> 3;                    // row within 8-row chunk
    const int c8 = ((lane & 7) ^ l8) << 3;       // swizzled source column chunk
    #pragma unroll
    for (int q = 0; q < 4; ++q) {
        const int r = wave * 32 + q * 8;         // wave-uniform row base
        const unsigned short* gp = gbase + (size_t)(r + l8) * strideElems + c8;
        unsigned short* lp = ldsBase + r * 64;   // wave-uniform; HW adds lane*16B
        __builtin_amdgcn_global_load_lds(
            (const __attribute__((address_space(1))) void*)gp,
            (__attribute__((address_space(3))) void*)lp,
            16, 0, 0);
    }
}

__device__ __forceinline__ void mfma_step(
    const unsigned short* As, const unsigned short* Bs,
    int waveM, int waveN, int lane, f32x4 acc[4][4])
{
    const int quad = lane >> 4;
    const int l15  = lane & 15;
    const int x7   = l15 & 7;                    // row&7 for all fragment rows
    #pragma unroll
    for (int s = 0; s < 2; ++s) {
        const int chunk = (s << 2) | quad;       // logical k-chunk (ko>>3)
        const int po = ((chunk ^ x7) << 3);      // swizzled element offset
        bf16x8 af[4], bfv[4];
        #pragma unroll
        for (int i = 0; i < 4; ++i)
            af[i] = *(const bf16x8*)(As + (waveM * 64 + i * 16 + l15) * 64 + po);
        #pragma unroll
        for (int j = 0; j < 4; ++j)
            bfv[j] = *(const bf16x8*)(Bs + (waveN * 64 + j * 16 + l15) * 64 + po);
        #pragma unroll
        for (int i = 0; i < 4; ++i)
            #pragma unroll
            for (int j = 0; j < 4; ++j)
                acc[i][j] = __builtin_amdgcn_mfma_f32_16x16x32_bf16(
                    af[i], bfv[j], acc[i][j], 0, 0, 0);
    }
}

// ---------------------------------------------------------------------------
// Kernel 3: ax split-K GEMM. Grid (64 row-tiles, KSPLIT). Block (rb, ks)
// computes axPart[ks] rows [rb*128,+128) over K slice [ks*1024,+1024), fp32.
// ---------------------------------------------------------------------------
__global__ __launch_bounds__(256) void k_ax(
    const unsigned short* __restrict__ xb,
    const unsigned short* __restrict__ Ab,     // [128][4096] bf16
    float* __restrict__ axPart)                // [KSPLIT][8192][128] fp32
{
    __shared__ __align__(16) unsigned short As[128 * 64];
    __shared__ __align__(16) unsigned short Bs[128 * 64];
    const int tid  = threadIdx.x;
    const int wave = tid >> 6, lane = tid & 63;
    const int waveM = wave >> 1, waveN = wave & 1;
    const int rowBase = blockIdx.x * 128;
    const int ks = blockIdx.y;
    const int k0 = ks * (DIM / KSPLIT);

    f32x4 acc[4][4] = {};

    for (int it = 0; it < (DIM / KSPLIT) / 64; ++it) {
        stage_lds(xb + (size_t)rowBase * DIM + k0 + it * 64, DIM, As, wave, lane);
        stage_lds(Ab + (size_t)0 * DIM       + k0 + it * 64, DIM, Bs, wave, lane);
        __syncthreads();
        mfma_step(As, Bs, waveM, waveN, lane, acc);
        __syncthreads();
    }

    float* outp = axPart + (size_t)ks * NTOK * KAUG;
    const int quad = lane >> 4, l15 = lane & 15;
    #pragma unroll
    for (int i = 0; i < 4; ++i) {
        #pragma unroll
        for (int j = 0; j < 4; ++j) {
            const int gc = waveN * 64 + j * 16 + l15;   // 0..127
            #pragma unroll
            for (int t = 0; t < 4; ++t) {
                const int gr = rowBase + waveM * 64 + i * 16 + quad * 4 + t;
                outp[(size_t)gr * KAUG + gc] = acc[i][j][t];
            }
        }
    }
}

// ---------------------------------------------------------------------------
// Kernel 3b: sum split-K partials, apply gate weights, emit bf16 cB
// ---------------------------------------------------------------------------
__global__ __launch_bounds__(256) void k_scale(
    const float* __restrict__ axPart,
    const float4* __restrict__ gate_out,
    unsigned short* __restrict__ cB)
{
    int idx = blockIdx.x * 256 + threadIdx.x;   // over NTOK*KAUG
    int n = idx >> 7;
    int j = idx & 127;
    float s = 0.f;
    #pragma unroll
    for (int ks = 0; ks < KSPLIT; ++ks)
        s += axPart[(size_t)ks * NTOK * KAUG + idx];
    float4 g = gate_out[n];
    int e  = j >> 4;
    int e0 = (int)g.x;
    int e1 = (int)g.y;
    float scale = (e == e0) ? 2.f * g.z : (e == e1) ? 2.f * g.w : 0.f;
    cB[idx] = f2bf(scale * s);
}

// ---------------------------------------------------------------------------
// Kernel 4: main GEMM, K = 4096 (xb,Wb) + 128 (cB,Bt) -> fp32 out [8192][4096]
// ---------------------------------------------------------------------------
__global__ __launch_bounds__(256) void k_main(
    const unsigned short* __restrict__ xb,    // [8192][4096] bf16
    const unsigned short* __restrict__ Wb,    // [4096][4096] bf16
    const unsigned short* __restrict__ cB,    // [8192][128]  bf16
    const unsigned short* __restrict__ Bt,    // [4096][128]  bf16
    float* __restrict__ out)                  // [8192][4096] fp32
{
    __shared__ __align__(16) unsigned short As[128 * 64];
    __shared__ __align__(16) unsigned short Bs[128 * 64];
    const int tid  = threadIdx.x;
    const int wave = tid >> 6, lane = tid & 63;
    const int waveM = wave >> 1, waveN = wave & 1;
    const int rowBase = blockIdx.y * 128;
    const int colBase = blockIdx.x * 128;

    f32x4 acc[4][4] = {};

    for (int it = 0; it < DIM / 64; ++it) {
        stage_lds(xb + (size_t)rowBase * DIM + it * 64, DIM, As, wave, lane);
        stage_lds(Wb + (size_t)colBase * DIM + it * 64, DIM, Bs, wave, lane);
        __syncthreads();
        mfma_step(As, Bs, waveM, waveN, lane, acc);
        __syncthreads();
    }
    // LoRA K-extension: 2 iterations over K=128 from cB / Bt (stride 128)
    for (int it = 0; it < KAUG / 64; ++it) {
        stage_lds(cB + (size_t)rowBase * KAUG + it * 64, KAUG, As, wave, lane);
        stage_lds(Bt + (size_t)colBase * KAUG + it * 64, KAUG, Bs, wave, lane);
        __syncthreads();
        mfma_step(As, Bs, waveM, waveN, lane, acc);
        __syncthreads();
    }

    const int quad = lane >> 4, l15 = lane & 15;
    #pragma unroll
    for (int i = 0; i < 4; ++i) {
        #pragma unroll
        for (int j = 0; j < 4; ++j) {
            const int gc = colBase + waveN * 64 + j * 16 + l15;
            #pragma unroll
            for (int t = 0; t < 4; ++t) {
                const int gr = rowBase + waveM * 64 + i * 16 + quad * 4 + t;
                out[(size_t)gr * DIM + gc] = acc[i][j][t];
            }
        }
    }
}

// ---------------------------------------------------------------------------
extern "C" void kernel_launch(void* const* d_in, const int* in_sizes, int n_in,
                              void* d_out, int out_size, void* d_ws, size_t ws_size,
                              hipStream_t stream) {
    (void)in_sizes; (void)n_in; (void)out_size; (void)ws_size;

    const float* x  = (const float*)d_in[0];  // [8192][4096]
    const float* bW = (const float*)d_in[1];  // [4096][4096]
    const float* gW = (const float*)d_in[2];  // [8][4096]
    const float* A  = (const float*)d_in[3];  // [8][16][4096] = [128][4096]
    const float* B  = (const float*)d_in[4];  // [8][4096][16]
    // d_in[5] = top_k (always 2)
    float* out = (float*)d_out;

    // workspace layout (all regions fully rewritten every launch)
    char* ws = (char*)d_ws;
    float4*         gate_out = (float4*)ws;                         //   128 KiB
    unsigned short* xb = (unsigned short*)(ws + (1u << 17));        //    64 MiB
    unsigned short* Wb = xb + (size_t)NTOK * DIM;                   //    32 MiB
    unsigned short* Ab = Wb + (size_t)DIM * DIM;                    //     1 MiB
    unsigned short* Bt = Ab + (size_t)KAUG * DIM;                   //     1 MiB
    unsigned short* cB = Bt + (size_t)DIM * KAUG;                   //     2 MiB
    float*      axPart = (float*)(cB + (size_t)NTOK * KAUG);        //    16 MiB
                                                                    // ~116 MiB

    k_gate<<<NTOK, 256, 0, stream>>>(x, gW, gate_out, (ushort4*)xb);
    k_cvt <<<(DIM * DIM / 4 + 255) / 256, 256, 0, stream>>>(
        (const float4*)bW, (ushort4*)Wb, DIM * DIM / 4);
    k_cvt <<<(KAUG * DIM / 4 + 255) / 256, 256, 0, stream>>>(
        (const float4*)A, (ushort4*)Ab, KAUG * DIM / 4);
    k_bt  <<<(DIM * KAUG) / 256, 256, 0, stream>>>(B, Bt);
    k_ax  <<<dim3(NTOK / 128, KSPLIT), 256, 0, stream>>>(xb, Ab, axPart);
    k_scale<<<(NTOK * KAUG) / 256, 256, 0, stream>>>(axPart, gate_out, cB);
    k_main<<<dim3(DIM / 128, NTOK / 128), 256, 0, stream>>>(xb, Wb, cB, Bt, out);
}